// Round 3
// baseline (439.004 us; speedup 1.0000x reference)
//
#include <hip/hip_runtime.h>
#include <cfloat>

// Problem constants
#define BB 64          // batch
#define CC 2048        // x channels
#define AR 2048        // x_art channels
#define DD 4096        // CC + AR
#define VV 256         // views
#define FF 4096        // hidden
#define OO 1000        // out channels

// ---------------------------------------------------------------------------
// Kernel 1: ragged max-pool over views -> pooled TRANSPOSED [D][64].
// 8192 waves x 32 rows each, 8 rows in flight per iteration (8 independent
// float4 loads). b/len hoisted per wave (32 rows never straddle a batch or
// the CC/ART boundary). Lane i covers v = 4i..4i+3.
// ---------------------------------------------------------------------------
__global__ __launch_bounds__(256) void pool_kernel(
    const float* __restrict__ x, const float* __restrict__ xart,
    const int* __restrict__ ll, float* __restrict__ pooledT)
{
    int waveId = (blockIdx.x * 256 + threadIdx.x) >> 6;   // 0..8191
    int lane   = threadIdx.x & 63;
    int row0   = waveId * 32;
    int b  = row0 >> 12;
    int d0 = row0 & 4095;
    int len = ll[b];
    if (len < 1) len = 1;
    const float* base = (d0 < CC)
        ? (x    + ((size_t)b * CC + d0)        * VV)
        : (xart + ((size_t)b * AR + (d0 - CC)) * VV);
    int v0  = lane * 4;
    int rem = len - v0;

    for (int r = 0; r < 32; r += 8) {
        const float* s = base + (size_t)r * VV;
        float m[8];
        #pragma unroll
        for (int j = 0; j < 8; ++j) m[j] = -FLT_MAX;
        if (rem > 0) {
            float4 a[8];
            #pragma unroll
            for (int j = 0; j < 8; ++j) a[j] = *(const float4*)(s + j * VV + v0);
            #pragma unroll
            for (int j = 0; j < 8; ++j) {
                m[j] = a[j].x;
                if (rem > 1) m[j] = fmaxf(m[j], a[j].y);
                if (rem > 2) m[j] = fmaxf(m[j], a[j].z);
                if (rem > 3) m[j] = fmaxf(m[j], a[j].w);
            }
        }
        #pragma unroll
        for (int off = 32; off > 0; off >>= 1) {
            #pragma unroll
            for (int j = 0; j < 8; ++j)
                m[j] = fmaxf(m[j], __shfl_xor(m[j], off, 64));
        }
        float wv = m[0];
        if (lane == 1) wv = m[1];
        else if (lane == 2) wv = m[2];
        else if (lane == 3) wv = m[3];
        else if (lane == 4) wv = m[4];
        else if (lane == 5) wv = m[5];
        else if (lane == 6) wv = m[6];
        else if (lane == 7) wv = m[7];
        if (lane < 8)
            pooledT[(size_t)(d0 + r + lane) * 64 + b] = wv;
    }
}

// ---------------------------------------------------------------------------
// Kernel 2a: wide split-K GEMM for F % 256 == 0 (GEMM1, GEMM2).
// part[chunk][b][f] = sum_{k in chunk} P[k][b] * W[k][f]
// Block 256 thr, tile 64b x 256f, thread tile 8b x 8f (f split tx*4 and
// 128+tx*4 so LDS reads stay at dense-b128 4-way, not 8-way).
// Double-buffered LDS, ONE barrier per 16-row stage: store(s+1 -> buf^1)
// precedes the barrier; compute(s) uses buf -- no cross-buffer race.
// P-reads are phase-uniform broadcasts (ty constant per 32-lane phase).
// ---------------------------------------------------------------------------
__global__ __launch_bounds__(256) void gemm_wide(
    const float* __restrict__ P, const float* __restrict__ W,
    float* __restrict__ part, int F, int kchunk)
{
    __shared__ float lds_p[2][16][64];
    __shared__ float lds_w[2][16][256];
    int t  = threadIdx.x;
    int tx = t & 31;           // f-group: cols tx*4 and 128+tx*4
    int ty = t >> 5;           // b-group: rows ty*8 .. ty*8+7
    int f0 = blockIdx.x * 256;
    int k0 = blockIdx.y * kchunk;
    int stages = kchunk >> 4;

    // staging map: row sr = t>>4 (0..15), col sc = (t&15)*4
    int sr = t >> 4;
    int sc = (t & 15) * 4;

    const float* Pg = P + (size_t)(k0 + sr) * 64 + sc;
    const float* Wg = W + (size_t)(k0 + sr) * F + f0 + sc;

    float acc[8][8];
    #pragma unroll
    for (int i = 0; i < 8; ++i)
        #pragma unroll
        for (int j = 0; j < 8; ++j) acc[i][j] = 0.f;

    // stage 0 -> buf 0
    {
        float4 pv  = *(const float4*)Pg;
        float4 wv0 = *(const float4*)(Wg);
        float4 wv1 = *(const float4*)(Wg + 64);
        float4 wv2 = *(const float4*)(Wg + 128);
        float4 wv3 = *(const float4*)(Wg + 192);
        *(float4*)&lds_p[0][sr][sc]       = pv;
        *(float4*)&lds_w[0][sr][sc]       = wv0;
        *(float4*)&lds_w[0][sr][64 + sc]  = wv1;
        *(float4*)&lds_w[0][sr][128 + sc] = wv2;
        *(float4*)&lds_w[0][sr][192 + sc] = wv3;
    }
    __syncthreads();

    for (int s = 0; s < stages; ++s) {
        int buf = s & 1;
        float4 pv, wv0, wv1, wv2, wv3;
        bool more = (s + 1 < stages);
        if (more) {                                  // issue next-stage loads
            const float* Pn = Pg + (size_t)(s + 1) * 16 * 64;
            const float* Wn = Wg + (size_t)(s + 1) * 16 * F;
            pv  = *(const float4*)Pn;
            wv0 = *(const float4*)(Wn);
            wv1 = *(const float4*)(Wn + 64);
            wv2 = *(const float4*)(Wn + 128);
            wv3 = *(const float4*)(Wn + 192);
        }
        #pragma unroll
        for (int kk = 0; kk < 16; ++kk) {
            float4 p0 = *(const float4*)&lds_p[buf][kk][ty * 8];
            float4 p1 = *(const float4*)&lds_p[buf][kk][ty * 8 + 4];
            float4 w0 = *(const float4*)&lds_w[buf][kk][tx * 4];
            float4 w1 = *(const float4*)&lds_w[buf][kk][128 + tx * 4];
            float pb[8] = {p0.x, p0.y, p0.z, p0.w, p1.x, p1.y, p1.z, p1.w};
            float wf[8] = {w0.x, w0.y, w0.z, w0.w, w1.x, w1.y, w1.z, w1.w};
            #pragma unroll
            for (int i = 0; i < 8; ++i)
                #pragma unroll
                for (int j = 0; j < 8; ++j)
                    acc[i][j] += pb[i] * wf[j];
        }
        if (more) {
            int nb = buf ^ 1;
            *(float4*)&lds_p[nb][sr][sc]       = pv;
            *(float4*)&lds_w[nb][sr][sc]       = wv0;
            *(float4*)&lds_w[nb][sr][64 + sc]  = wv1;
            *(float4*)&lds_w[nb][sr][128 + sc] = wv2;
            *(float4*)&lds_w[nb][sr][192 + sc] = wv3;
            __syncthreads();
        }
    }

    float* dst = part + (size_t)blockIdx.y * 64 * F;
    #pragma unroll
    for (int i = 0; i < 8; ++i) {
        float* r = dst + (size_t)(ty * 8 + i) * F + f0;
        *(float4*)(r + tx * 4)       = make_float4(acc[i][0], acc[i][1], acc[i][2], acc[i][3]);
        *(float4*)(r + 128 + tx * 4) = make_float4(acc[i][4], acc[i][5], acc[i][6], acc[i][7]);
    }
}

// ---------------------------------------------------------------------------
// Kernel 2b: 128-wide split-K GEMM with F-tail handling (GEMM3, F=1000).
// Same as round 2: tile 64b x 128f, thread 4b x 8f, register prefetch.
// ---------------------------------------------------------------------------
__global__ __launch_bounds__(256) void gemm_partial(
    const float* __restrict__ P, const float* __restrict__ W,
    float* __restrict__ part, int F, int kchunk)
{
    __shared__ float lds_p[16][64];
    __shared__ float lds_w[16][128];
    int t  = threadIdx.x;
    int tx = t & 15, ty = t >> 4;
    int f0 = blockIdx.x * 128;
    int k0 = blockIdx.y * kchunk;
    int stages = kchunk >> 4;
    int c1 = f0 + tx * 4;
    int c2 = f0 + 64 + tx * 4;
    bool v2 = (c2 + 3 < F);

    float acc[4][8];
    #pragma unroll
    for (int i = 0; i < 4; ++i)
        #pragma unroll
        for (int j = 0; j < 8; ++j) acc[i][j] = 0.f;

    int k = k0 + ty;
    float4 pv  = *(const float4*)(P + (size_t)k * 64 + tx * 4);
    const float* wr = W + (size_t)k * F;
    float4 wv0 = *(const float4*)(wr + c1);
    float4 wv1;
    if (v2) wv1 = *(const float4*)(wr + c2);
    else {
        wv1.x = (c2     < F) ? wr[c2]     : 0.f;
        wv1.y = (c2 + 1 < F) ? wr[c2 + 1] : 0.f;
        wv1.z = (c2 + 2 < F) ? wr[c2 + 2] : 0.f;
        wv1.w = (c2 + 3 < F) ? wr[c2 + 3] : 0.f;
    }

    for (int s = 0; s < stages; ++s) {
        __syncthreads();
        *(float4*)&lds_p[ty][tx * 4]      = pv;
        *(float4*)&lds_w[ty][tx * 4]      = wv0;
        *(float4*)&lds_w[ty][64 + tx * 4] = wv1;
        __syncthreads();
        if (s + 1 < stages) {
            int kn = k0 + (s + 1) * 16 + ty;
            pv = *(const float4*)(P + (size_t)kn * 64 + tx * 4);
            const float* wrn = W + (size_t)kn * F;
            wv0 = *(const float4*)(wrn + c1);
            if (v2) wv1 = *(const float4*)(wrn + c2);
            else {
                wv1.x = (c2     < F) ? wrn[c2]     : 0.f;
                wv1.y = (c2 + 1 < F) ? wrn[c2 + 1] : 0.f;
                wv1.z = (c2 + 2 < F) ? wrn[c2 + 2] : 0.f;
                wv1.w = (c2 + 3 < F) ? wrn[c2 + 3] : 0.f;
            }
        }
        #pragma unroll
        for (int kk = 0; kk < 16; ++kk) {
            float4 p4 = *(const float4*)&lds_p[kk][ty * 4];
            float4 wa = *(const float4*)&lds_w[kk][tx * 4];
            float4 wb = *(const float4*)&lds_w[kk][64 + tx * 4];
            #pragma unroll
            for (int i = 0; i < 4; ++i) {
                float pi = (i == 0) ? p4.x : (i == 1) ? p4.y : (i == 2) ? p4.z : p4.w;
                acc[i][0] += pi * wa.x;  acc[i][1] += pi * wa.y;
                acc[i][2] += pi * wa.z;  acc[i][3] += pi * wa.w;
                acc[i][4] += pi * wb.x;  acc[i][5] += pi * wb.y;
                acc[i][6] += pi * wb.z;  acc[i][7] += pi * wb.w;
            }
        }
    }

    float* dst = part + (size_t)blockIdx.y * 64 * F;
    #pragma unroll
    for (int i = 0; i < 4; ++i) {
        float* r = dst + (size_t)(ty * 4 + i) * F;
        *(float4*)(r + c1) = make_float4(acc[i][0], acc[i][1], acc[i][2], acc[i][3]);
        if (v2)
            *(float4*)(r + c2) = make_float4(acc[i][4], acc[i][5], acc[i][6], acc[i][7]);
        else {
            if (c2     < F) r[c2]     = acc[i][4];
            if (c2 + 1 < F) r[c2 + 1] = acc[i][5];
            if (c2 + 2 < F) r[c2 + 2] = acc[i][6];
            if (c2 + 3 < F) r[c2 + 3] = acc[i][7];
        }
    }
}

// ---------------------------------------------------------------------------
// Kernel 3: reduce split-K partials + bias + ReLU -> TRANSPOSED [F][64].
// ---------------------------------------------------------------------------
__global__ __launch_bounds__(256) void reduce_bias_relu_T(
    const float* __restrict__ part, const float* __restrict__ bias,
    float* __restrict__ outT, int nchunk, int F)
{
    __shared__ float lds[64 * 17];
    int t  = threadIdx.x;
    int f0 = blockIdx.x * 16;
    int fl = t & 15;
    int ty = t >> 4;
    float bv = bias[f0 + fl];
    float acc[4];
    #pragma unroll
    for (int j = 0; j < 4; ++j) acc[j] = bv;
    for (int c = 0; c < nchunk; ++c) {
        const float* p = part + ((size_t)c * 64) * F + f0 + fl;
        #pragma unroll
        for (int j = 0; j < 4; ++j)
            acc[j] += p[(size_t)(j * 16 + ty) * F];
    }
    #pragma unroll
    for (int j = 0; j < 4; ++j)
        lds[(j * 16 + ty) * 17 + fl] = fmaxf(acc[j], 0.f);
    __syncthreads();
    #pragma unroll
    for (int j = 0; j < 4; ++j) {
        int idx = j * 256 + t;
        int f = idx >> 6;
        int b = idx & 63;
        outT[(size_t)(f0 + f) * 64 + b] = lds[b * 17 + f];
    }
}

// ---------------------------------------------------------------------------
// Kernel 4: final reduce + bias (no ReLU) -> d_out [64][1000].
// ---------------------------------------------------------------------------
__global__ __launch_bounds__(256) void reduce_out_kernel(
    const float* __restrict__ part, const float* __restrict__ bias,
    float* __restrict__ out, int nchunk)
{
    int idx = blockIdx.x * 256 + threadIdx.x;
    if (idx >= BB * OO) return;
    int b = idx / OO, f = idx - b * OO;
    float v = bias[f];
    const float* p = part + (size_t)b * OO + f;
    #pragma unroll 8
    for (int c = 0; c < nchunk; ++c)
        v += p[(size_t)c * 64 * OO];
    out[idx] = v;
}

// ---------------------------------------------------------------------------
extern "C" void kernel_launch(void* const* d_in, const int* in_sizes, int n_in,
                              void* d_out, int out_size, void* d_ws, size_t ws_size,
                              hipStream_t stream) {
    const float* x    = (const float*)d_in[0];
    const float* xart = (const float*)d_in[1];
    const int*   ll   = (const int*)d_in[2];
    const float* w1   = (const float*)d_in[3];
    const float* b1   = (const float*)d_in[4];
    const float* w2   = (const float*)d_in[5];
    const float* b2   = (const float*)d_in[6];
    const float* w3   = (const float*)d_in[7];
    const float* b3   = (const float*)d_in[8];
    float* out = (float*)d_out;

    float* pooledT = (float*)d_ws;
    float* h1T     = pooledT + (size_t)DD * 64;
    float* h2T     = h1T     + (size_t)FF * 64;
    float* part    = h2T     + (size_t)FF * 64;

    size_t actBytes = (size_t)(DD + FF + FF) * 64 * sizeof(float);   // 3 MiB
    size_t avail    = (ws_size > actBytes) ? ws_size - actBytes : 0;
    size_t plane1   = (size_t)64 * FF * sizeof(float);               // 1 MiB
    int nk1 = 8;
    if (avail >= 32 * plane1)      nk1 = 32;   // part = 32 MiB
    else if (avail >= 16 * plane1) nk1 = 16;
    size_t plane3 = (size_t)64 * OO * sizeof(float);                 // 250 KiB
    int nk3 = (avail >= 64 * plane3) ? 64 : 32;
    int kchunk1 = DD / nk1;
    int kchunk3 = FF / nk3;

    // 1) ragged max-pool -> pooledT [4096][64]
    pool_kernel<<<2048, 256, 0, stream>>>(x, xart, ll, pooledT);

    // 2) h1 = relu(pooled @ w1 + b1): 16 f-tiles x nk1 chunks
    gemm_wide<<<dim3(FF / 256, nk1), 256, 0, stream>>>(pooledT, w1, part, FF, kchunk1);
    reduce_bias_relu_T<<<FF / 16, 256, 0, stream>>>(part, b1, h1T, nk1, FF);

    // 3) h2 = relu(h1 @ w2 + b2)
    gemm_wide<<<dim3(FF / 256, nk1), 256, 0, stream>>>(h1T, w2, part, FF, kchunk1);
    reduce_bias_relu_T<<<FF / 16, 256, 0, stream>>>(part, b2, h2T, nk1, FF);

    // 4) out = h2 @ w3 + b3: 8 f-tiles (tail), nk3 chunks
    gemm_partial<<<dim3(8, nk3), 256, 0, stream>>>(h2T, w3, part, OO, kchunk3);
    reduce_out_kernel<<<(BB * OO + 255) / 256, 256, 0, stream>>>(part, b3, out, nk3);
}